// Round 4
// baseline (431.913 us; speedup 1.0000x reference)
//
#include <hip/hip_runtime.h>
#include <hip/hip_bf16.h>

typedef __attribute__((ext_vector_type(8))) short bf16x8;
typedef __attribute__((ext_vector_type(4))) float f32x4;

static __device__ __forceinline__ unsigned short f2bf(float f){
  __hip_bfloat16 h = __float2bfloat16(f);
  return *reinterpret_cast<unsigned short*>(&h);
}
static __device__ __forceinline__ float bf2f(unsigned short u){
  unsigned int x = ((unsigned int)u) << 16;
  return *reinterpret_cast<float*>(&x);
}
static __device__ __forceinline__ void gload16(const void* g, void* l){
  __builtin_amdgcn_global_load_lds((__attribute__((address_space(1))) void*)g,
                                   (__attribute__((address_space(3))) void*)l, 16, 0, 0);
}
static __device__ __forceinline__ f32x4 mfma16(bf16x8 a, bf16x8 b, f32x4 c){
  return __builtin_amdgcn_mfma_f32_16x16x32_bf16(a, b, c, 0, 0, 0);
}

// ---------------- merged f32 -> bf16 convert (drug + protein + 8 weights) ----------------
struct CvtArgs { const float* drug; const float* protein; const float* w[8]; };
__global__ __launch_bounds__(256) void k_cvt_all(CvtArgs a,
                                                 unsigned short* __restrict__ Xd,
                                                 unsigned short* __restrict__ Xp,
                                                 unsigned short* __restrict__ Wb){
  for (int i = blockIdx.x*256 + threadIdx.x; i < 5767168; i += 1048576){
    float4 v; ushort4* dst;
    if (i < 1048576){
      v = reinterpret_cast<const float4*>(a.drug)[i];
      dst = reinterpret_cast<ushort4*>(Xd) + i;
    } else if (i < 5242880){
      const int j = i - 1048576;
      v = reinterpret_cast<const float4*>(a.protein)[j];
      dst = reinterpret_cast<ushort4*>(Xp) + j;
    } else {
      const int j = i - 5242880;
      v = reinterpret_cast<const float4*>(a.w[j>>16])[j & 65535];
      dst = reinterpret_cast<ushort4*>(Wb) + j;
    }
    ushort4 o;
    o.x = f2bf(v.x); o.y = f2bf(v.y); o.z = f2bf(v.z); o.w = f2bf(v.w);
    *dst = o;
  }
}

// ---------------- 128x128 BT GEMM body, K=512, BK=64, swizzled LDS ----------------
// SIDE 0 = drug projections, SIDE 1 = protein projections
template<int SIDE>
__device__ __forceinline__ void proj_side(int id,
    const unsigned short* __restrict__ A, const unsigned short* __restrict__ W3,
    const float* __restrict__ b0, const float* __restrict__ b1, const float* __restrict__ b2,
    unsigned short* __restrict__ o01, unsigned short* __restrict__ oV,
    const float* __restrict__ alphap, char* AsB, char* BsB){
  constexpr int LSH = SIDE ? 10 : 8;
  constexpr int MPX = SIDE ? 32 : 8;
  const int xcd = id & 7, j = id >> 3;
  const int m0 = (xcd*MPX + j/12) * 128;
  const int n0 = (j % 12) * 128;
  const int t = threadIdx.x, l = t&63, w = t>>6;
  const int wm = w>>1, wn = w&1;
  f32x4 acc[4][4] = {};
  const char* Ab = (const char*)A + (size_t)m0*1024;
  const char* Wp = (const char*)W3 + (size_t)n0*1024;
  const int grow = t>>3;                       // 0..31 (row within 32-row issue)
  const int gcolb = ((t&7) ^ (grow&7))*16;     // pre-swizzled source column

  for (int kt=0; kt<8; ++kt){
    __syncthreads();
    const int kb = kt*128;
    for (int i=0;i<4;++i){
      gload16(Ab + (size_t)(i*32 + grow)*1024 + kb + gcolb, AsB + i*4096 + w*1024);
      gload16(Wp + (size_t)(i*32 + grow)*1024 + kb + gcolb, BsB + i*4096 + w*1024);
    }
    __syncthreads();
    bf16x8 a[4][2], b[4][2];
    for (int i=0;i<4;++i){
      const int ra = wm*64 + i*16 + (l&15);
      const int rb = wn*64 + i*16 + (l&15);
      for (int ks=0;ks<2;++ks){
        const int cb = ks*64 + (l>>4)*16;
        a[i][ks] = *(const bf16x8*)(AsB + ra*128 + (cb ^ ((ra&7)<<4)));
        b[i][ks] = *(const bf16x8*)(BsB + rb*128 + (cb ^ ((rb&7)<<4)));
      }
    }
    __builtin_amdgcn_s_setprio(1);
    for (int i=0;i<4;++i)
      for (int jj=0;jj<4;++jj)
        for (int ks=0;ks<2;++ks)
          acc[i][jj] = mfma16(a[i][ks], b[jj][ks], acc[i][jj]);
    __builtin_amdgcn_s_setprio(0);
  }

  const float al = alphap[0];
  const float sg = 1.f/(1.f + __expf(-al));
  const int Lseq = 1 << LSH;
  for (int i=0;i<4;++i){
    for (int jj=0;jj<4;++jj){
      const int nn = n0 + wn*64 + jj*16 + (l&15);
      const int g = nn>>9, c = nn&511, h = c>>6, d = c&63;
      const float bv = (g==0 ? b0 : (g==1 ? b1 : b2))[c];
      for (int r=0;r<4;++r){
        const int mm = m0 + wm*64 + i*16 + (l>>4)*4 + r;
        float v = acc[i][jj][r] + bv;
        const int bb = mm >> LSH, pos = mm & (Lseq-1);
        if (g < 2){
          if (SIDE==0) v *= (g==0 ? sg : (1.f-sg)) * 0.125f;
          const int c2 = g*64 + d;
          *(unsigned short*)((char*)o01 + ((size_t)(bb*8+h)*Lseq + pos)*256
                             + ((c2*2) ^ ((pos&15)<<4))) = f2bf(v);
        } else {
          if (SIDE==1)
            *(unsigned short*)((char*)oV + ((size_t)(bb*8+h)*64 + d)*2048
                               + ((pos*2) ^ ((d&15)<<4))) = f2bf(v);
          else
            oV[ ((size_t)(bb*8+h)*64 + d)*256 + pos ] = f2bf(v);
        }
      }
    }
  }
}

__global__ __launch_bounds__(256) void k_proj_all(
    const unsigned short* __restrict__ Xd, const unsigned short* __restrict__ Xp,
    const unsigned short* __restrict__ Wb,
    const float* __restrict__ bqd, const float* __restrict__ bkd, const float* __restrict__ bvd,
    const float* __restrict__ bkp, const float* __restrict__ bqp, const float* __restrict__ bvp,
    unsigned short* __restrict__ Dm, unsigned short* __restrict__ Pm,
    unsigned short* __restrict__ Vpt, unsigned short* __restrict__ Vdt,
    const float* __restrict__ alphap){
  __shared__ unsigned short As[128*64];
  __shared__ unsigned short Bs[128*64];
  if (blockIdx.x < 3072)
    proj_side<1>(blockIdx.x, Xp, Wb + 3*262144, bkp, bqp, bvp, Pm, Vpt, alphap,
                 (char*)As, (char*)Bs);
  else
    proj_side<0>(blockIdx.x - 3072, Xd, Wb + 0*262144, bqd, bkd, bvd, Dm, Vdt, alphap,
                 (char*)As, (char*)Bs);
}

// ---------------- output projection body (N=512, K=512, BK=64, f32 nt out) ----------------
template<int MPX>
__device__ __forceinline__ void oproj_side(int id,
    const unsigned short* __restrict__ A, const unsigned short* __restrict__ W,
    const float* __restrict__ bias, float* __restrict__ out, char* AsB, char* BsB){
  const int xcd = id & 7, j = id >> 3;
  const int m0 = (xcd*MPX + j/4) * 128;
  const int n0 = (j & 3) * 128;
  const int t = threadIdx.x, l = t&63, w = t>>6;
  const int wm = w>>1, wn = w&1;
  f32x4 acc[4][4] = {};
  const char* Ab = (const char*)A + (size_t)m0*1024;
  const char* Wp = (const char*)W + (size_t)n0*1024;
  const int grow = t>>3;
  const int gcolb = ((t&7) ^ (grow&7))*16;

  for (int kt=0; kt<8; ++kt){
    __syncthreads();
    const int kb = kt*128;
    for (int i=0;i<4;++i){
      gload16(Ab + (size_t)(i*32 + grow)*1024 + kb + gcolb, AsB + i*4096 + w*1024);
      gload16(Wp + (size_t)(i*32 + grow)*1024 + kb + gcolb, BsB + i*4096 + w*1024);
    }
    __syncthreads();
    bf16x8 a[4][2], b[4][2];
    for (int i=0;i<4;++i){
      const int ra = wm*64 + i*16 + (l&15);
      const int rb = wn*64 + i*16 + (l&15);
      for (int ks=0;ks<2;++ks){
        const int cb = ks*64 + (l>>4)*16;
        a[i][ks] = *(const bf16x8*)(AsB + ra*128 + (cb ^ ((ra&7)<<4)));
        b[i][ks] = *(const bf16x8*)(BsB + rb*128 + (cb ^ ((rb&7)<<4)));
      }
    }
    __builtin_amdgcn_s_setprio(1);
    for (int i=0;i<4;++i)
      for (int jj=0;jj<4;++jj)
        for (int ks=0;ks<2;++ks)
          acc[i][jj] = mfma16(a[i][ks], b[jj][ks], acc[i][jj]);
    __builtin_amdgcn_s_setprio(0);
  }
  for (int i=0;i<4;++i)
    for (int jj=0;jj<4;++jj){
      const int nn = n0 + wn*64 + jj*16 + (l&15);
      const float bv = bias[nn];
      for (int r=0;r<4;++r){
        const int mm = m0 + wm*64 + i*16 + (l>>4)*4 + r;
        __builtin_nontemporal_store(acc[i][jj][r] + bv, &out[ (size_t)mm*512 + nn ]);
      }
    }
}

__global__ __launch_bounds__(256) void k_oproj_all(
    const unsigned short* __restrict__ Cd, const unsigned short* __restrict__ Cp,
    const unsigned short* __restrict__ Wb,
    const float* __restrict__ bod, const float* __restrict__ bop,
    float* __restrict__ outd, float* __restrict__ outp){
  __shared__ unsigned short As[128*64];
  __shared__ unsigned short Bs[128*64];
  if (blockIdx.x < 1024)
    oproj_side<32>(blockIdx.x, Cp, Wb + 7*262144, bop, outp, (char*)As, (char*)Bs);
  else
    oproj_side<8>(blockIdx.x - 1024, Cd, Wb + 6*262144, bod, outd, (char*)As, (char*)Bs);
}

// ---------------- single-pass QK^T + exp + rowsum; spills bf16 expS ----------------
__global__ __launch_bounds__(256) void k_qks(const unsigned short* __restrict__ Dm,
                                             const unsigned short* __restrict__ Pm,
                                             unsigned short* __restrict__ expS,
                                             float* __restrict__ rinv){
  __shared__ unsigned short Ds[128*128];
  __shared__ unsigned short Ps[128*128];
  const int id = blockIdx.x, xcd = id & 7, j = id >> 3;
  const int bh = xcd*32 + (j>>1), qt = j&1;
  const int t = threadIdx.x, l = t&63, w = t>>6;
  char* DsB = (char*)Ds; char* PsB = (char*)Ps;
  const char* dsrc = (const char*)Dm + ((size_t)bh*256 + qt*128)*256;
  const char* psrc = (const char*)Pm + (size_t)bh*1024*256;
  char* egbase = (char*)expS + ((size_t)bh*256 + qt*128)*2048;
  const int lofs = w*1024;

  for (int i=0;i<8;++i)
    gload16(dsrc + i*4096 + lofs + l*16, DsB + i*4096 + lofs);

  float rs[2][4] = {};
  for (int pt=0; pt<8; ++pt){
    __syncthreads();            // prev copy done / Ps free
    for (int i=0;i<8;++i)
      gload16(psrc + pt*32768 + i*4096 + lofs + l*16, PsB + i*4096 + lofs);
    __syncthreads();            // Ps (and Ds) resident
    f32x4 acc[2][8] = {};
    for (int kt=0;kt<4;++kt){
      bf16x8 a[2];
      for (int fm=0;fm<2;++fm){
        const int row = w*32 + fm*16 + (l&15);
        const int byteo = (kt*64 + (l>>4)*16) ^ ((row&15)<<4);
        a[fm] = *(const bf16x8*)(DsB + row*256 + byteo);
      }
      __builtin_amdgcn_s_setprio(1);
      for (int fn=0;fn<8;++fn){
        const int row = fn*16 + (l&15);
        const int byteo = (kt*64 + (l>>4)*16) ^ ((row&15)<<4);
        bf16x8 b = *(const bf16x8*)(PsB + row*256 + byteo);
        acc[0][fn] = mfma16(a[0], b, acc[0][fn]);
        acc[1][fn] = mfma16(a[1], b, acc[1][fn]);
      }
      __builtin_amdgcn_s_setprio(0);
    }
    __syncthreads();            // done reading Ps -> reuse as exp staging
    for (int fm=0;fm<2;++fm)
      for (int fn=0;fn<8;++fn)
        for (int r=0;r<4;++r){
          float e = __expf(acc[fm][fn][r]);
          rs[fm][r] += e;
          const int q = w*32 + fm*16 + (l>>4)*4 + r;
          const int p = fn*16 + (l&15);
          *(unsigned short*)(PsB + q*256 + ((p*2) ^ ((q&15)<<4))) = f2bf(e);
        }
    __syncthreads();            // exp tile complete
    for (int i=0;i<4;++i){
      const int idx = i*256 + t;
      const int row = idx>>3, colb = (idx&7)*32;
      int4 v0 = *(const int4*)(PsB + row*256 + colb);
      int4 v1 = *(const int4*)(PsB + row*256 + colb + 16);
      char* gp = egbase + (size_t)row*2048 + pt*256 + colb;
      *(int4*)gp = v0;
      *(int4*)(gp+16) = v1;
    }
  }
  for (int m=1;m<16;m<<=1)
    for (int fm=0;fm<2;++fm)
      for (int r=0;r<4;++r)
        rs[fm][r] += __shfl_xor(rs[fm][r], m, 64);
  if ((l&15)==0){
    for (int fm=0;fm<2;++fm)
      for (int r=0;r<4;++r){
        const int row = w*32 + fm*16 + (l>>4)*4 + r;
        rinv[ (size_t)bh*256 + qt*128 + row ] = 1.f/rs[fm][r];
      }
  }
}

// ---------------- fused normalize-write-attn + ctx_d = P@Vp ----------------
__global__ __launch_bounds__(256) void k_nctxd(const unsigned short* __restrict__ expS,
                                               const unsigned short* __restrict__ Vpt,
                                               const float* __restrict__ rinv,
                                               float* __restrict__ attn,
                                               unsigned short* __restrict__ Cd){
  __shared__ unsigned short Es[128*128];
  __shared__ unsigned short Vs[64*128];
  __shared__ float ri[128];
  const int id = blockIdx.x, xcd = id & 7, j = id >> 3;
  const int bh = xcd*32 + (j>>1), qt = j&1;
  const int b = bh>>3, h = bh&7;
  const int t = threadIdx.x, l = t&63, w = t>>6;
  char* EsB = (char*)Es; char* VsB = (char*)Vs;
  if (t < 128) ri[t] = rinv[ (size_t)bh*256 + qt*128 + t ];
  const char* esrc = (const char*)expS + ((size_t)bh*256 + qt*128)*2048;
  const char* vsrc = (const char*)Vpt + (size_t)bh*64*2048;
  const int lofs = w*1024;
  f32x4 accd[2][4] = {};

  for (int pt=0; pt<8; ++pt){
    __syncthreads();
    for (int i=0;i<8;++i){
      const int ib = i*4096 + lofs + l*16;
      gload16(esrc + (size_t)(ib>>8)*2048 + pt*256 + (ib&255), EsB + i*4096 + lofs);
    }
    for (int i=0;i<4;++i){
      const int ib = i*4096 + lofs + l*16;
      gload16(vsrc + (size_t)(ib>>8)*2048 + pt*256 + (ib&255), VsB + i*4096 + lofs);
    }
    __syncthreads();
    for (int kt=0;kt<4;++kt){
      bf16x8 a[2], bb[4];
      for (int fm=0;fm<2;++fm){
        const int row = w*32 + fm*16 + (l&15);
        const int byteo = (kt*64 + (l>>4)*16) ^ ((row&15)<<4);
        a[fm] = *(const bf16x8*)(EsB + row*256 + byteo);
      }
      for (int fn=0;fn<4;++fn){
        const int row = fn*16 + (l&15);
        const int byteo = (kt*64 + (l>>4)*16) ^ ((row&15)<<4);
        bb[fn] = *(const bf16x8*)(VsB + row*256 + byteo);
      }
      __builtin_amdgcn_s_setprio(1);
      for (int fm=0;fm<2;++fm)
        for (int fn=0;fn<4;++fn)
          accd[fm][fn] = mfma16(a[fm], bb[fn], accd[fm][fn]);
      __builtin_amdgcn_s_setprio(0);
      // normalized attn write from the A-fragments (nontemporal: never re-read)
      for (int fm=0;fm<2;++fm){
        const int row = w*32 + fm*16 + (l&15);
        const float rv = ri[row];
        f32x4 lo, hi;
        lo[0] = bf2f((unsigned short)a[fm][0]) * rv;
        lo[1] = bf2f((unsigned short)a[fm][1]) * rv;
        lo[2] = bf2f((unsigned short)a[fm][2]) * rv;
        lo[3] = bf2f((unsigned short)a[fm][3]) * rv;
        hi[0] = bf2f((unsigned short)a[fm][4]) * rv;
        hi[1] = bf2f((unsigned short)a[fm][5]) * rv;
        hi[2] = bf2f((unsigned short)a[fm][6]) * rv;
        hi[3] = bf2f((unsigned short)a[fm][7]) * rv;
        float* op = attn + ((size_t)bh*256 + qt*128 + row)*1024 + pt*128 + kt*32 + (l>>4)*8;
        __builtin_nontemporal_store(lo, (f32x4*)op);
        __builtin_nontemporal_store(hi, (f32x4*)(op+4));
      }
    }
  }
  for (int fm=0;fm<2;++fm)
    for (int fn=0;fn<4;++fn)
      for (int r=0;r<4;++r){
        const int row = w*32 + fm*16 + (l>>4)*4 + r;
        const float v = accd[fm][fn][r] * ri[row];
        const int col = fn*16 + (l&15);
        Cd[ ((size_t)b*256 + qt*128 + row)*512 + h*64 + col ] = f2bf(v);
      }
}

// ---------------- ctx_p = expS^T @ (rinv*Vd) ----------------
__global__ __launch_bounds__(256) void k_ctxp(const unsigned short* __restrict__ expS,
                                              const unsigned short* __restrict__ Vdt,
                                              const float* __restrict__ rinv,
                                              unsigned short* __restrict__ Cp){
  __shared__ unsigned short As[128*40];
  __shared__ unsigned short Bs[64*40];
  __shared__ float ri[256];
  const int id = blockIdx.x, xcd = id & 7, j = id >> 3;
  const int bh = xcd*32 + (j>>3), mt = j&7;
  const int b = bh>>3, h = bh&7;
  const int t = threadIdx.x, l = t&63, w = t>>6;
  ri[t] = rinv[ (size_t)bh*256 + t ];
  const char* ebase = (const char*)expS + (size_t)bh*256*2048;
  const unsigned short* vbase = Vdt + (size_t)bh*16384;
  f32x4 acc[2][4] = {};
  for (int kt=0; kt<8; ++kt){
    __syncthreads();
    for (int i=0;i<4;++i){
      const int idx = i*256 + t;
      const int ql = idx>>5, p4 = idx&31;
      const int qg = kt*32 + ql;
      ushort4 v = *(const ushort4*)(ebase + (size_t)qg*2048 + ((mt*256 + p4*8) ^ ((qg&15)<<4)));
      As[(p4*4+0)*40 + ql] = v.x;
      As[(p4*4+1)*40 + ql] = v.y;
      As[(p4*4+2)*40 + ql] = v.z;
      As[(p4*4+3)*40 + ql] = v.w;
    }
    for (int i=0;i<2;++i){
      const int idx = i*256 + t;
      const int row = idx>>3, c4 = idx&7;
      ushort4 vv = *(const ushort4*)(vbase + (size_t)row*256 + kt*32 + c4*4);
      const float* rp = &ri[kt*32 + c4*4];
      Bs[row*40 + c4*4+0] = f2bf(bf2f(vv.x) * rp[0]);
      Bs[row*40 + c4*4+1] = f2bf(bf2f(vv.y) * rp[1]);
      Bs[row*40 + c4*4+2] = f2bf(bf2f(vv.z) * rp[2]);
      Bs[row*40 + c4*4+3] = f2bf(bf2f(vv.w) * rp[3]);
    }
    __syncthreads();
    bf16x8 a[2], bb[4];
    for (int fm=0;fm<2;++fm)
      a[fm] = *(const bf16x8*)(As + (w*32 + fm*16 + (l&15))*40 + (l>>4)*8);
    for (int fn=0;fn<4;++fn)
      bb[fn] = *(const bf16x8*)(Bs + (fn*16 + (l&15))*40 + (l>>4)*8);
    for (int fm=0;fm<2;++fm)
      for (int fn=0;fn<4;++fn)
        acc[fm][fn] = mfma16(a[fm], bb[fn], acc[fm][fn]);
  }
  for (int fm=0;fm<2;++fm)
    for (int fn=0;fn<4;++fn)
      for (int r=0;r<4;++r){
        const int row = mt*128 + w*32 + fm*16 + (l>>4)*4 + r;
        const int col = fn*16 + (l&15);
        Cp[ ((size_t)b*1024 + row)*512 + h*64 + col ] = f2bf(acc[fm][fn][r]);
      }
}

extern "C" void kernel_launch(void* const* d_in, const int* in_sizes, int n_in,
                              void* d_out, int out_size, void* d_ws, size_t ws_size,
                              hipStream_t stream){
  const float* drug    = (const float*)d_in[0];
  const float* protein = (const float*)d_in[1];
  const float* Wqd=(const float*)d_in[2];  const float* bqd=(const float*)d_in[3];
  const float* Wkp=(const float*)d_in[4];  const float* bkp=(const float*)d_in[5];
  const float* Wvp=(const float*)d_in[6];  const float* bvp=(const float*)d_in[7];
  const float* Wqp=(const float*)d_in[8];  const float* bqp=(const float*)d_in[9];
  const float* Wkd=(const float*)d_in[10]; const float* bkd=(const float*)d_in[11];
  const float* Wvd=(const float*)d_in[12]; const float* bvd=(const float*)d_in[13];
  const float* alpha=(const float*)d_in[14];
  const float* Wod=(const float*)d_in[15]; const float* bod=(const float*)d_in[16];
  const float* Wop=(const float*)d_in[17]; const float* bop=(const float*)d_in[18];

  char* ws = (char*)d_ws;
  unsigned short* expS = (unsigned short*)(ws + 0);          // [bh][256][1024] bf16, p-swizzled
  unsigned short* Xd   = (unsigned short*)(ws + 0);          // 8192x512 bf16  (dead after proj)
  unsigned short* Xp   = (unsigned short*)(ws + 8388608);    // 32768x512 bf16 (dead after proj)
  unsigned short* Wb   = (unsigned short*)(ws + 134217728);  // 8 x 512x512 bf16
  unsigned short* Dm   = (unsigned short*)(ws + 138412032);  // [bh][256][128] swizzled (dead after qks)
  unsigned short* Cd   = (unsigned short*)(ws + 138412032);  // overlay
  unsigned short* Pm   = (unsigned short*)(ws + 155189248);  // [bh][1024][128] swizzled (dead after qks)
  unsigned short* Cp   = (unsigned short*)(ws + 155189248);  // overlay
  unsigned short* Vpt  = (unsigned short*)(ws + 222298112);  // [bh][64][1024] swizzled
  unsigned short* Vdt  = (unsigned short*)(ws + 255852544);  // [bh][64][256] linear
  float*          rinv = (float*)         (ws + 264241152);  // [bh][256]

  float* attn = (float*)d_out;
  float* outd = (float*)d_out + 67108864;
  float* outp = (float*)d_out + 71303168;

  CvtArgs ca;
  ca.drug = drug; ca.protein = protein;
  ca.w[0]=Wqd; ca.w[1]=Wkd; ca.w[2]=Wvd; ca.w[3]=Wkp; ca.w[4]=Wqp; ca.w[5]=Wvp; ca.w[6]=Wod; ca.w[7]=Wop;
  k_cvt_all<<<4096, 256, 0, stream>>>(ca, Xd, Xp, Wb);

  // fused projections (protein blocks 0..3071, drug blocks 3072..3839)
  k_proj_all<<<3840, 256, 0, stream>>>(Xd, Xp, Wb, bqd, bkd, bvd, bkp, bqp, bvp,
                                       Dm, Pm, Vpt, Vdt, alpha);

  // attention: single pass, spill bf16 expS + rinv
  k_qks<<<512, 256, 0, stream>>>(Dm, Pm, expS, rinv);

  // normalize + write f32 attn + ctx_d
  k_nctxd<<<512, 256, 0, stream>>>(expS, Vpt, rinv, attn, Cd);

  // ctx_p
  k_ctxp<<<2048, 256, 0, stream>>>(expS, Vdt, rinv, Cp);

  // output projections (protein blocks 0..1023, drug 1024..1279)
  k_oproj_all<<<1280, 256, 0, stream>>>(Cd, Cp, Wb, bod, bop, outd, outp);
}